// Round 4
// baseline (133.731 us; speedup 1.0000x reference)
//
#include <hip/hip_runtime.h>
#include <hip/hip_bf16.h>

#define N_PTS  4096
#define NB     9
#define C      256
#define MID    64
#define KNBR   16
#define NROWS  (N_PTS * NB)          // 36864

typedef __attribute__((ext_vector_type(8))) short     short8;   // 8 bf16 (A/B frag)
typedef __attribute__((ext_vector_type(4))) float     f32x4;    // C/D frag
typedef __attribute__((ext_vector_type(2))) float     f32x2;
typedef __attribute__((ext_vector_type(4))) unsigned short ush4;

static __device__ __forceinline__ unsigned short f2bf(float f) {
    union { __hip_bfloat16 h; unsigned short u; } cv;
    cv.h = __float2bfloat16(f);          // RNE; compiler fuses pairs into v_cvt_pk_bf16_f32
    return cv.u;
}
static __device__ __forceinline__ float bf2f(unsigned short s) {
    union { unsigned u; float f; } v; v.u = ((unsigned)s) << 16;
    return v.f;
}
static __device__ __forceinline__ f32x2 bf2x2(unsigned u) {
    union { unsigned u; float f; } lo, hi;
    lo.u = u << 16;
    hi.u = u & 0xffff0000u;
    return (f32x2){lo.f, hi.f};
}
static __device__ __forceinline__ unsigned packbf(float a, float b) {
    return (unsigned)f2bf(a) | ((unsigned)f2bf(b) << 16);
}

#if __has_builtin(__builtin_elementwise_fma)
static __device__ __forceinline__ f32x2 fma2(f32x2 a, f32x2 b, f32x2 c) {
    return __builtin_elementwise_fma(a, b, c);
}
#else
static __device__ __forceinline__ f32x2 fma2(f32x2 a, f32x2 b, f32x2 c) {
    f32x2 r; r.x = fmaf(a.x, b.x, c.x); r.y = fmaf(a.y, b.y, c.y); return r;
}
#endif

// ---------------------------------------------------------------------------
// Kernel 1: h(bf16) = s_feats(f32) @ W_proj(f32).  M=36864 K=256 N=256.
#define LDK 40            // 32 + 8 pad (ushorts); row stride 80B, 16B aligned
__global__ __launch_bounds__(256) void k_proj(const float* __restrict__ A,
                                              const float* __restrict__ W,
                                              unsigned short* __restrict__ H) {
    __shared__ unsigned short As[128 * LDK];
    __shared__ unsigned short Bs[128 * LDK];
    const int tid = threadIdx.x;
    const int r0  = blockIdx.x * 128;
    const int n0  = blockIdx.y * 128;
    const int wave = tid >> 6, lane = tid & 63;
    const int wm = wave >> 1, wn = wave & 1;
    const int lr = lane & 15, lg = lane >> 4;

    f32x4 acc[4][4];
#pragma unroll
    for (int a = 0; a < 4; ++a)
#pragma unroll
        for (int b = 0; b < 4; ++b) acc[a][b] = (f32x4){0.f, 0.f, 0.f, 0.f};

    for (int k0 = 0; k0 < C; k0 += 32) {
        __syncthreads();
#pragma unroll
        for (int rep = 0; rep < 4; ++rep) {
            const int e   = rep * 256 + tid;      // float4 unit, 8 per row
            const int row = e >> 3;
            const int c4  = (e & 7) << 2;
            const float4 v = *reinterpret_cast<const float4*>(&A[(size_t)(r0 + row) * C + k0 + c4]);
            ush4 s = { f2bf(v.x), f2bf(v.y), f2bf(v.z), f2bf(v.w) };
            *reinterpret_cast<ush4*>(&As[row * LDK + c4]) = s;
        }
#pragma unroll
        for (int rep = 0; rep < 4; ++rep) {
            const int e = rep * 256 + tid;        // float4 unit, 32 per k-row
            const int k = e >> 5;
            const int j = (e & 31) << 2;
            const float4 v = *reinterpret_cast<const float4*>(&W[(size_t)(k0 + k) * C + n0 + j]);
            Bs[(j + 0) * LDK + k] = f2bf(v.x);
            Bs[(j + 1) * LDK + k] = f2bf(v.y);
            Bs[(j + 2) * LDK + k] = f2bf(v.z);
            Bs[(j + 3) * LDK + k] = f2bf(v.w);
        }
        __syncthreads();

        short8 af[4], bfr[4];
#pragma unroll
        for (int mf = 0; mf < 4; ++mf)
            af[mf] = *reinterpret_cast<const short8*>(&As[(wm * 64 + mf * 16 + lr) * LDK + lg * 8]);
#pragma unroll
        for (int nf = 0; nf < 4; ++nf)
            bfr[nf] = *reinterpret_cast<const short8*>(&Bs[(wn * 64 + nf * 16 + lr) * LDK + lg * 8]);
#pragma unroll
        for (int mf = 0; mf < 4; ++mf)
#pragma unroll
            for (int nf = 0; nf < 4; ++nf)
                acc[mf][nf] = __builtin_amdgcn_mfma_f32_16x16x32_bf16(af[mf], bfr[nf], acc[mf][nf], 0, 0, 0);
    }
#pragma unroll
    for (int mf = 0; mf < 4; ++mf)
#pragma unroll
        for (int nf = 0; nf < 4; ++nf) {
            const int col = n0 + wn * 64 + nf * 16 + lr;
#pragma unroll
            for (int r = 0; r < 4; ++r) {
                const int row = r0 + wm * 64 + mf * 16 + lg * 4 + r;
                H[(size_t)row * C + col] = f2bf(acc[mf][nf][r]);
            }
        }
}

// ---------------------------------------------------------------------------
// Kernel 2: CG contraction + residual + fused per-degree LN.
// Block = 256 thr = 4 waves = 2 points; wave PAIR per point; lane owns 2 ch.
__global__ __launch_bounds__(256) void k_cg_ln(const unsigned short* __restrict__ Hb,
                                               const float* __restrict__ s_feats,
                                               const float* __restrict__ pts,
                                               const float* __restrict__ cg,
                                               const int*   __restrict__ nbr,
                                               const float* __restrict__ ln_w,
                                               const float* __restrict__ ln_b,
                                               unsigned short* __restrict__ Xb,
                                               unsigned short* __restrict__ Yb) {
    __shared__ float cg_s[729];
    __shared__ float sh_s[2][KNBR][NB];
    __shared__ float w_s[2][KNBR * 81];
    __shared__ int   idx_s[2][KNBR];
    __shared__ float red_s[2][2][4];

    const int tid  = threadIdx.x;
    const int wave = tid >> 6;
    const int lane = tid & 63;
    const int p    = wave >> 1;       // which point within block
    const int half = wave & 1;        // which 128-channel half
    const int n    = blockIdx.x * 2 + p;
    const int ch   = half * 128 + lane * 2;

    for (int e = tid; e < 729; e += 256) cg_s[e] = cg[e];

    if (tid < 2 * KNBR) {
        const int pp = tid >> 4, kk = tid & 15;
        const int nn = blockIdx.x * 2 + pp;
        const int idx = nbr[nn * KNBR + kk];
        idx_s[pp][kk] = idx;
        const float px = pts[idx * 3 + 0] - pts[nn * 3 + 0];
        const float py = pts[idx * 3 + 1] - pts[nn * 3 + 1];
        const float pz = pts[idx * 3 + 2] - pts[nn * 3 + 2];
        const float r  = sqrtf(px * px + py * py + pz * pz);
        const float iv = 1.f / (r + 1e-8f);
        const float dx = px * iv, dy = py * iv, dz = pz * iv;
        const float c1 = 0.4886025119029199f;
        const float c2 = 1.0925484305920792f;
        sh_s[pp][kk][0] = 0.28209479177387814f;
        sh_s[pp][kk][1] = c1 * dy;
        sh_s[pp][kk][2] = c1 * dz;
        sh_s[pp][kk][3] = c1 * dx;
        sh_s[pp][kk][4] = c2 * dx * dy;
        sh_s[pp][kk][5] = c2 * dy * dz;
        sh_s[pp][kk][6] = 0.31539156525252005f * (3.f * dz * dz - 1.f);
        sh_s[pp][kk][7] = c2 * dx * dz;
        sh_s[pp][kk][8] = 0.5462742152960396f * (dx * dx - dy * dy);
    }
    __syncthreads();

    // w[k,i,o] = sum_j sh[k][j] * cg[i*81 + j*9 + o]; wave pair covers 1296 entries
    for (int t = half * 64 + lane; t < KNBR * 81; t += 128) {
        const int k   = t / 81;
        const int rem = t - k * 81;
        const int i   = rem / 9;
        const int o   = rem - i * 9;
        float s = 0.f;
#pragma unroll
        for (int j = 0; j < 9; ++j) s = fmaf(sh_s[p][k][j], cg_s[i * 81 + j * 9 + o], s);
        w_s[p][t] = s;
    }
    __syncthreads();

    // gather + contraction: lane owns channels (ch, ch+1) as one u32 load
    f32x2 acc[9];
#pragma unroll
    for (int o = 0; o < 9; ++o) acc[o] = (f32x2){0.f, 0.f};

    for (int k = 0; k < KNBR; ++k) {
        const unsigned* hrow =
            reinterpret_cast<const unsigned*>(Hb + (size_t)idx_s[p][k] * (NB * C) + ch);
        unsigned q[9];
#pragma unroll
        for (int i = 0; i < 9; ++i) q[i] = hrow[i * (C / 2)];   // 9 independent loads
        const float* wk = &w_s[p][k * 81];
#pragma unroll
        for (int i = 0; i < 9; ++i) {
            const f32x2 h = bf2x2(q[i]);
#pragma unroll
            for (int o = 0; o < 9; ++o) {
                const float w = wk[i * 9 + o];
                acc[o] = fma2(h, (f32x2){w, w}, acc[o]);
            }
        }
    }

    // residual add (fp32 s_feats)
    const float2* sf = reinterpret_cast<const float2*>(s_feats + (size_t)n * (NB * C) + ch);
    f32x2 v[9];
#pragma unroll
    for (int o = 0; o < 9; ++o) {
        const float2 s2 = sf[o * (C / 2)];
        v[o].x = acc[o].x * (1.f / (float)KNBR) + s2.x;
        v[o].y = acc[o].y * (1.f / (float)KNBR) + s2.y;
    }

    // LN stats: wave-local then combine across the wave pair
    float s0 = v[0].x + v[0].y;
    float s1 = v[0].x * v[0].x + v[0].y * v[0].y;
    float s2 = 0.f, s3 = 0.f;
#pragma unroll
    for (int o = 1; o < 4; ++o) s2 += v[o].x * v[o].x + v[o].y * v[o].y;
#pragma unroll
    for (int o = 4; o < 9; ++o) s3 += v[o].x * v[o].x + v[o].y * v[o].y;
#pragma unroll
    for (int off = 32; off >= 1; off >>= 1) {
        s0 += __shfl_xor(s0, off);
        s1 += __shfl_xor(s1, off);
        s2 += __shfl_xor(s2, off);
        s3 += __shfl_xor(s3, off);
    }
    if (lane == 0) {
        red_s[p][half][0] = s0; red_s[p][half][1] = s1;
        red_s[p][half][2] = s2; red_s[p][half][3] = s3;
    }
    __syncthreads();
    s0 = red_s[p][0][0] + red_s[p][1][0];
    s1 = red_s[p][0][1] + red_s[p][1][1];
    s2 = red_s[p][0][2] + red_s[p][1][2];
    s3 = red_s[p][0][3] + red_s[p][1][3];

    const float mean0 = s0 * (1.f / 256.f);
    const float nrm0  = s1 * (1.f / 256.f) - mean0 * mean0;
    const float nrm1  = s2 * (1.f / 768.f);
    const float nrm2  = s3 * (1.f / 1280.f);
    const float r0 = rsqrtf(nrm0 + 1e-5f);
    const float r1 = rsqrtf(nrm1 + 1e-5f);
    const float r2 = rsqrtf(nrm2 + 1e-5f);

    const float2 lw0 = *reinterpret_cast<const float2*>(ln_w + ch);
    const float2 lw1 = *reinterpret_cast<const float2*>(ln_w + C + ch);
    const float2 lw2 = *reinterpret_cast<const float2*>(ln_w + 2 * C + ch);
    const float2 lb0 = *reinterpret_cast<const float2*>(ln_b + ch);

    unsigned* xo = reinterpret_cast<unsigned*>(Xb + (size_t)n * (NB * C) + ch);
    unsigned* yo = reinterpret_cast<unsigned*>(Yb + (size_t)n * (NB * C) + ch);
#pragma unroll
    for (int o = 0; o < 9; ++o) xo[o * (C / 2)] = packbf(v[o].x, v[o].y);
    yo[0] = packbf((v[0].x - mean0) * r0 * lw0.x + lb0.x,
                   (v[0].y - mean0) * r0 * lw0.y + lb0.y);
#pragma unroll
    for (int o = 1; o < 4; ++o)
        yo[o * (C / 2)] = packbf(v[o].x * r1 * lw1.x, v[o].y * r1 * lw1.y);
#pragma unroll
    for (int o = 4; o < 9; ++o)
        yo[o * (C / 2)] = packbf(v[o].x * r2 * lw2.x, v[o].y * r2 * lw2.y);
}

// ---------------------------------------------------------------------------
// Kernel 3: z(bf16) = y(bf16) @ W_ff1(f32).  M=36864 K=256 N=64.
__global__ __launch_bounds__(256) void k_ff1(const unsigned short* __restrict__ Yb,
                                             const float* __restrict__ W1,
                                             unsigned short* __restrict__ Zb) {
    __shared__ unsigned short As[128 * LDK];
    __shared__ unsigned short Bs[64 * LDK];
    const int tid = threadIdx.x;
    const int r0  = blockIdx.x * 128;
    const int wave = tid >> 6, lane = tid & 63;
    const int wm = wave >> 1, wn = wave & 1;
    const int lr = lane & 15, lg = lane >> 4;

    f32x4 acc[4][2];
#pragma unroll
    for (int a = 0; a < 4; ++a) { acc[a][0] = (f32x4){0.f,0.f,0.f,0.f}; acc[a][1] = (f32x4){0.f,0.f,0.f,0.f}; }

    for (int k0 = 0; k0 < C; k0 += 32) {
        __syncthreads();
#pragma unroll
        for (int rep = 0; rep < 4; ++rep) {
            const int e   = rep * 256 + tid;     // ush4 unit, 8 per row
            const int row = e >> 3;
            const int c4  = (e & 7) << 2;
            ush4 s = *reinterpret_cast<const ush4*>(&Yb[(size_t)(r0 + row) * C + k0 + c4]);
            *reinterpret_cast<ush4*>(&As[row * LDK + c4]) = s;
        }
#pragma unroll
        for (int rep = 0; rep < 2; ++rep) {
            const int e = rep * 256 + tid;       // float4 unit, 16 per k-row (64 n)
            const int k = e >> 4;
            const int j = (e & 15) << 2;
            const float4 v = *reinterpret_cast<const float4*>(&W1[(size_t)(k0 + k) * MID + j]);
            Bs[(j + 0) * LDK + k] = f2bf(v.x);
            Bs[(j + 1) * LDK + k] = f2bf(v.y);
            Bs[(j + 2) * LDK + k] = f2bf(v.z);
            Bs[(j + 3) * LDK + k] = f2bf(v.w);
        }
        __syncthreads();

        short8 af[4], bfr[2];
#pragma unroll
        for (int mf = 0; mf < 4; ++mf)
            af[mf] = *reinterpret_cast<const short8*>(&As[(wm * 64 + mf * 16 + lr) * LDK + lg * 8]);
#pragma unroll
        for (int nf = 0; nf < 2; ++nf)
            bfr[nf] = *reinterpret_cast<const short8*>(&Bs[(wn * 32 + nf * 16 + lr) * LDK + lg * 8]);
#pragma unroll
        for (int mf = 0; mf < 4; ++mf)
#pragma unroll
            for (int nf = 0; nf < 2; ++nf)
                acc[mf][nf] = __builtin_amdgcn_mfma_f32_16x16x32_bf16(af[mf], bfr[nf], acc[mf][nf], 0, 0, 0);
    }
#pragma unroll
    for (int mf = 0; mf < 4; ++mf)
#pragma unroll
        for (int nf = 0; nf < 2; ++nf) {
            const int col = wn * 32 + nf * 16 + lr;
#pragma unroll
            for (int r = 0; r < 4; ++r) {
                const int row = r0 + wm * 64 + mf * 16 + lg * 4 + r;
                Zb[(size_t)row * MID + col] = f2bf(acc[mf][nf][r]);
            }
        }
}

// ---------------------------------------------------------------------------
// Kernel 4: gate head. after = z0 @ W_gate; G[n][0:64]=silu, [64:192]=sigmoid.
__global__ __launch_bounds__(192) void k_gate(const unsigned short* __restrict__ Zb,
                                              const float* __restrict__ Wg,
                                              float* __restrict__ G) {
    __shared__ float wgs[64 * 192];
    __shared__ float z0s[16 * 64];
    const int tid = threadIdx.x;
    const int n0  = blockIdx.x * 16;

    for (int e = tid; e < 64 * 192; e += 192) wgs[e] = Wg[e];
    for (int e = tid; e < 16 * 64; e += 192) {
        const int r = e >> 6, m = e & 63;
        z0s[e] = bf2f(Zb[(size_t)(n0 + r) * (NB * MID) + m]);
    }
    __syncthreads();

    const int j = tid;
    for (int r = 0; r < 16; ++r) {
        float acc = 0.f;
        for (int m0 = 0; m0 < 64; m0 += 4) {
            const float4 zv = *reinterpret_cast<const float4*>(&z0s[r * 64 + m0]);
            acc = fmaf(zv.x, wgs[(m0 + 0) * 192 + j], acc);
            acc = fmaf(zv.y, wgs[(m0 + 1) * 192 + j], acc);
            acc = fmaf(zv.z, wgs[(m0 + 2) * 192 + j], acc);
            acc = fmaf(zv.w, wgs[(m0 + 3) * 192 + j], acc);
        }
        const float sig = 1.f / (1.f + expf(-acc));
        G[(size_t)(n0 + r) * 192 + j] = (j < 64) ? acc * sig : sig;
    }
}

// ---------------------------------------------------------------------------
// Kernel 5: out(f32) = gated(z) @ W_ff2 + x.  M=36864 K=64 N=256.
#define LDK64 72          // 64 + 8 pad; row stride 144B, 16B aligned
__global__ __launch_bounds__(256) void k_final(const unsigned short* __restrict__ Zb,
                                               const float* __restrict__ G,
                                               const float* __restrict__ W2,
                                               const unsigned short* __restrict__ Xb,
                                               float* __restrict__ OUT) {
    __shared__ unsigned short As[128 * LDK64];
    __shared__ unsigned short Bs[128 * LDK64];
    const int tid = threadIdx.x;
    const int r0  = blockIdx.x * 128;
    const int n0  = blockIdx.y * 128;
    const int wave = tid >> 6, lane = tid & 63;
    const int wm = wave >> 1, wn = wave & 1;
    const int lr = lane & 15, lg = lane >> 4;

    // stage A: gated-z rows (2 threads per row, 32 k each)
    {
        const int arow = tid >> 1;
        const int kh   = (tid & 1) * 32;
        const int grow = r0 + arow;
        const int nn   = grow / 9;
        const int ii   = grow - nn * 9;
        if (ii == 0) {
            const float* gp = &G[(size_t)nn * 192 + kh];
#pragma unroll
            for (int j = 0; j < 32; j += 4) {
                const float4 g = *reinterpret_cast<const float4*>(&gp[j]);
                ush4 s = { f2bf(g.x), f2bf(g.y), f2bf(g.z), f2bf(g.w) };
                *reinterpret_cast<ush4*>(&As[arow * LDK64 + kh + j]) = s;
            }
        } else {
            const float* gm = &G[(size_t)nn * 192 + ((ii < 4) ? 64 : 128) + kh];
            const unsigned short* zr = &Zb[(size_t)nn * (NB * MID) + ii * MID + kh];
#pragma unroll
            for (int j = 0; j < 32; j += 4) {
                const ush4 zv = *reinterpret_cast<const ush4*>(&zr[j]);
                const float4 g = *reinterpret_cast<const float4*>(&gm[j]);
                ush4 s = { f2bf(bf2f(zv.x) * g.x), f2bf(bf2f(zv.y) * g.y),
                           f2bf(bf2f(zv.z) * g.z), f2bf(bf2f(zv.w) * g.w) };
                *reinterpret_cast<ush4*>(&As[arow * LDK64 + kh + j]) = s;
            }
        }
    }
    // stage B: Bs[n][k] = W2[k][n0+n], full 64 x 128 tile
#pragma unroll
    for (int rep = 0; rep < 8; ++rep) {
        const int e = rep * 256 + tid;           // float4 unit, 32 per k-row
        const int k = e >> 5;
        const int j = (e & 31) << 2;
        const float4 v = *reinterpret_cast<const float4*>(&W2[(size_t)k * C + n0 + j]);
        Bs[(j + 0) * LDK64 + k] = f2bf(v.x);
        Bs[(j + 1) * LDK64 + k] = f2bf(v.y);
        Bs[(j + 2) * LDK64 + k] = f2bf(v.z);
        Bs[(j + 3) * LDK64 + k] = f2bf(v.w);
    }
    __syncthreads();

    f32x4 acc[4][4];
#pragma unroll
    for (int a = 0; a < 4; ++a)
#pragma unroll
        for (int b = 0; b < 4; ++b) acc[a][b] = (f32x4){0.f, 0.f, 0.f, 0.f};

#pragma unroll
    for (int ks = 0; ks < 2; ++ks) {
        short8 af[4], bfr[4];
#pragma unroll
        for (int mf = 0; mf < 4; ++mf)
            af[mf] = *reinterpret_cast<const short8*>(&As[(wm * 64 + mf * 16 + lr) * LDK64 + ks * 32 + lg * 8]);
#pragma unroll
        for (int nf = 0; nf < 4; ++nf)
            bfr[nf] = *reinterpret_cast<const short8*>(&Bs[(wn * 64 + nf * 16 + lr) * LDK64 + ks * 32 + lg * 8]);
#pragma unroll
        for (int mf = 0; mf < 4; ++mf)
#pragma unroll
            for (int nf = 0; nf < 4; ++nf)
                acc[mf][nf] = __builtin_amdgcn_mfma_f32_16x16x32_bf16(af[mf], bfr[nf], acc[mf][nf], 0, 0, 0);
    }

#pragma unroll
    for (int mf = 0; mf < 4; ++mf)
#pragma unroll
        for (int nf = 0; nf < 4; ++nf) {
            const int col = n0 + wn * 64 + nf * 16 + lr;
#pragma unroll
            for (int r = 0; r < 4; ++r) {
                const int row = r0 + wm * 64 + mf * 16 + lg * 4 + r;
                OUT[(size_t)row * C + col] = acc[mf][nf][r] + bf2f(Xb[(size_t)row * C + col]);
            }
        }
}

// ---------------------------------------------------------------------------
extern "C" void kernel_launch(void* const* d_in, const int* in_sizes, int n_in,
                              void* d_out, int out_size, void* d_ws, size_t ws_size,
                              hipStream_t stream) {
    const float* s_feats = (const float*)d_in[0];
    const float* s_pts   = (const float*)d_in[1];
    const float* cg      = (const float*)d_in[2];
    const float* W_proj  = (const float*)d_in[3];
    const float* ln_w    = (const float*)d_in[4];
    const float* ln_b    = (const float*)d_in[5];
    const float* W_ff1   = (const float*)d_in[6];
    const float* W_gate  = (const float*)d_in[7];
    const float* W_ff2   = (const float*)d_in[8];
    const int*   nbr     = (const int*)d_in[9];
    float* out = (float*)d_out;

    unsigned short* Hb = (unsigned short*)d_ws;            // NROWS*C bf16
    unsigned short* Xb = Hb + (size_t)NROWS * C;           // NROWS*C bf16 (shortcut)
    unsigned short* Yb = Xb + (size_t)NROWS * C;           // NROWS*C bf16 (LN output)
    unsigned short* Zb = Yb + (size_t)NROWS * C;           // NROWS*MID bf16
    float* G = (float*)(Zb + (size_t)NROWS * MID);         // N_PTS*192 f32

    k_proj  <<<dim3(NROWS / 128, 2), 256, 0, stream>>>(s_feats, W_proj, Hb);
    k_cg_ln <<<N_PTS / 2,            256, 0, stream>>>(Hb, s_feats, s_pts, cg, nbr, ln_w, ln_b, Xb, Yb);
    k_ff1   <<<NROWS / 128,          256, 0, stream>>>(Yb, W_ff1, Zb);
    k_gate  <<<N_PTS / 16,           192, 0, stream>>>(Zb, W_gate, G);
    k_final <<<dim3(NROWS / 128, 2), 256, 0, stream>>>(Zb, G, W_ff2, Xb, out);
}

// Round 7
// 131.891 us; speedup vs baseline: 1.0140x; 1.0140x over previous
//
#include <hip/hip_runtime.h>
#include <hip/hip_bf16.h>

#define N_PTS  4096
#define NB     9
#define C      256
#define MID    64
#define KNBR   16
#define NROWS  (N_PTS * NB)          // 36864

typedef __attribute__((ext_vector_type(8))) short          short8;  // 8 bf16 (A/B frag)
typedef __attribute__((ext_vector_type(4))) float          f32x4;   // C/D frag
typedef __attribute__((ext_vector_type(4))) unsigned short ush4;
typedef __attribute__((ext_vector_type(8))) unsigned short ush8;

static __device__ __forceinline__ unsigned short f2bf(float f) {
    union { __hip_bfloat16 h; unsigned short u; } cv;
    cv.h = __float2bfloat16(f);          // RNE; pairs fuse into v_cvt_pk_bf16_f32
    return cv.u;
}
static __device__ __forceinline__ float bf2f(unsigned short s) {
    union { unsigned u; float f; } v; v.u = ((unsigned)s) << 16;
    return v.f;
}
static __device__ __forceinline__ unsigned packbf(float a, float b) {
    return (unsigned)f2bf(a) | ((unsigned)f2bf(b) << 16);
}

// ---------------------------------------------------------------------------
// Kernel 1: h(bf16) = s_feats(f32) @ W_proj(f32).  M=36864 K=256 N=256.
#define LDK 40            // 32 + 8 pad (ushorts); row stride 80B, 16B aligned
__global__ __launch_bounds__(256) void k_proj(const float* __restrict__ A,
                                              const float* __restrict__ W,
                                              unsigned short* __restrict__ H) {
    __shared__ unsigned short As[128 * LDK];
    __shared__ unsigned short Bs[128 * LDK];
    const int tid = threadIdx.x;
    const int r0  = blockIdx.x * 128;
    const int n0  = blockIdx.y * 128;
    const int wave = tid >> 6, lane = tid & 63;
    const int wm = wave >> 1, wn = wave & 1;
    const int lr = lane & 15, lg = lane >> 4;

    f32x4 acc[4][4];
#pragma unroll
    for (int a = 0; a < 4; ++a)
#pragma unroll
        for (int b = 0; b < 4; ++b) acc[a][b] = (f32x4){0.f, 0.f, 0.f, 0.f};

    for (int k0 = 0; k0 < C; k0 += 32) {
        __syncthreads();
#pragma unroll
        for (int rep = 0; rep < 4; ++rep) {
            const int e   = rep * 256 + tid;      // float4 unit, 8 per row
            const int row = e >> 3;
            const int c4  = (e & 7) << 2;
            const float4 v = *reinterpret_cast<const float4*>(&A[(size_t)(r0 + row) * C + k0 + c4]);
            ush4 s = { f2bf(v.x), f2bf(v.y), f2bf(v.z), f2bf(v.w) };
            *reinterpret_cast<ush4*>(&As[row * LDK + c4]) = s;
        }
#pragma unroll
        for (int rep = 0; rep < 4; ++rep) {
            const int e = rep * 256 + tid;        // float4 unit, 32 per k-row
            const int k = e >> 5;
            const int j = (e & 31) << 2;
            const float4 v = *reinterpret_cast<const float4*>(&W[(size_t)(k0 + k) * C + n0 + j]);
            Bs[(j + 0) * LDK + k] = f2bf(v.x);
            Bs[(j + 1) * LDK + k] = f2bf(v.y);
            Bs[(j + 2) * LDK + k] = f2bf(v.z);
            Bs[(j + 3) * LDK + k] = f2bf(v.w);
        }
        __syncthreads();

        short8 af[4], bfr[4];
#pragma unroll
        for (int mf = 0; mf < 4; ++mf)
            af[mf] = *reinterpret_cast<const short8*>(&As[(wm * 64 + mf * 16 + lr) * LDK + lg * 8]);
#pragma unroll
        for (int nf = 0; nf < 4; ++nf)
            bfr[nf] = *reinterpret_cast<const short8*>(&Bs[(wn * 64 + nf * 16 + lr) * LDK + lg * 8]);
#pragma unroll
        for (int mf = 0; mf < 4; ++mf)
#pragma unroll
            for (int nf = 0; nf < 4; ++nf)
                acc[mf][nf] = __builtin_amdgcn_mfma_f32_16x16x32_bf16(af[mf], bfr[nf], acc[mf][nf], 0, 0, 0);
    }
#pragma unroll
    for (int mf = 0; mf < 4; ++mf)
#pragma unroll
        for (int nf = 0; nf < 4; ++nf) {
            const int col = n0 + wn * 64 + nf * 16 + lr;
#pragma unroll
            for (int r = 0; r < 4; ++r) {
                const int row = r0 + wm * 64 + mf * 16 + lg * 4 + r;
                H[(size_t)row * C + col] = f2bf(acc[mf][nf][r]);
            }
        }
}

// ---------------------------------------------------------------------------
// Kernel 2: CG contraction via MFMA + residual + fused per-degree LN.
// One block (4 waves) per point n. D[o,c] = sum_ki w[ki,o] * h[gather(ki)][c],
// M=16 (o, 9 valid), N=256 (c), K=160 (ki, 144 valid; wT zero-padded so B may
// hold garbage for ki>=144). Plain k_proj-style fragments — NO tr-read.
//   A: wT[16][168] row-major [o][ki] bf16 (stride 336B, 16B-aligned, 2-way banks)
//   B: Bs[256][40]  [c][ki-chunk] bf16, restaged per 32-ki chunk via scalar
//      ds_write_b16 transpose (write ~2-way banks, read b128 2-way banks).
// Epilogue: D -> LDS (reuse Bs) -> residual + per-degree LN -> Xb, Yb.
__global__ __launch_bounds__(256) void k_cg_ln(const unsigned short* __restrict__ Hb,
                                               const float* __restrict__ s_feats,
                                               const float* __restrict__ pts,
                                               const float* __restrict__ cg,
                                               const int*   __restrict__ nbr,
                                               const float* __restrict__ ln_w,
                                               const float* __restrict__ ln_b,
                                               unsigned short* __restrict__ Xb,
                                               unsigned short* __restrict__ Yb) {
    __shared__ unsigned short Bs[256 * 40];      // 20 KB, current chunk transposed
    __shared__ unsigned short wT[16 * 168];      // 5.25 KB, A operand
    __shared__ float cg_s[729];
    __shared__ float sh_s[KNBR][NB];
    __shared__ int   idx_s[KNBR];
    __shared__ float red_s[2][4];

    const int tid  = threadIdx.x;
    const int n    = blockIdx.x;
    const int wv   = tid >> 6;
    const int lane = tid & 63;
    const int g16  = lane >> 4;
    const int l16  = lane & 15;

    // ---- prologue: zero wT, load cg, neighbor indices + SH ----
    {
        unsigned* w32 = reinterpret_cast<unsigned*>(wT);
        for (int e = tid; e < (16 * 168) / 2; e += 256) w32[e] = 0u;
    }
    for (int e = tid; e < 729; e += 256) cg_s[e] = cg[e];
    if (tid < KNBR) {
        const int idx = nbr[n * KNBR + tid];
        idx_s[tid] = idx;
        const float px = pts[idx * 3 + 0] - pts[n * 3 + 0];
        const float py = pts[idx * 3 + 1] - pts[n * 3 + 1];
        const float pz = pts[idx * 3 + 2] - pts[n * 3 + 2];
        const float r  = sqrtf(px * px + py * py + pz * pz);
        const float iv = 1.f / (r + 1e-8f);
        const float dx = px * iv, dy = py * iv, dz = pz * iv;
        const float c1 = 0.4886025119029199f;
        const float c2 = 1.0925484305920792f;
        sh_s[tid][0] = 0.28209479177387814f;
        sh_s[tid][1] = c1 * dy;
        sh_s[tid][2] = c1 * dz;
        sh_s[tid][3] = c1 * dx;
        sh_s[tid][4] = c2 * dx * dy;
        sh_s[tid][5] = c2 * dy * dz;
        sh_s[tid][6] = 0.31539156525252005f * (3.f * dz * dz - 1.f);
        sh_s[tid][7] = c2 * dx * dz;
        sh_s[tid][8] = 0.5462742152960396f * (dx * dx - dy * dy);
    }
    __syncthreads();

    // ---- fill wT[o][ki] = sum_j sh[kk][j] * cg[ii*81 + j*9 + o], ki=kk*9+ii ----
    for (int t = tid; t < 144 * 9; t += 256) {
        const int ki = t / 9;
        const int o  = t - ki * 9;
        const int kk = ki / 9;
        const int ii = ki - kk * 9;
        float s = 0.f;
#pragma unroll
        for (int j = 0; j < 9; ++j) s = fmaf(sh_s[kk][j], cg_s[ii * 81 + j * 9 + o], s);
        wT[o * 168 + ki] = f2bf(s);
    }
    // (wT visibility covered by the barriers inside chunk 0)

    const int r = tid & 31;     // ki row within chunk (fast across lanes)
    const int s = tid >> 5;     // 32-channel segment

    f32x4 acc[4];
#pragma unroll
    for (int i = 0; i < 4; ++i) acc[i] = (f32x4){0.f, 0.f, 0.f, 0.f};

    for (int cc = 0; cc < 5; ++cc) {
        const int nrows = (cc == 4) ? 16 : 32;   // ki 144..159 are w=0: skip staging
        ush8 q[4];
        if (r < nrows) {
            const int ki = cc * 32 + r;
            const int kk = ki / 9;
            const int ii = ki - kk * 9;
            const unsigned short* hrow = Hb + (size_t)(idx_s[kk] * NB + ii) * C + s * 32;
#pragma unroll
            for (int u = 0; u < 4; ++u)
                q[u] = *reinterpret_cast<const ush8*>(hrow + u * 8);
        }
        __syncthreads();   // previous chunk's ds_reads drained before overwrite
        if (r < nrows) {
#pragma unroll
            for (int u = 0; u < 4; ++u) {
                const unsigned short* qe = reinterpret_cast<const unsigned short*>(&q[u]);
#pragma unroll
                for (int e = 0; e < 8; ++e)
                    Bs[(s * 32 + u * 8 + e) * 40 + r] = qe[e];
            }
        }
        __syncthreads();   // staged chunk visible

        // fragments exactly like k_proj (proven layout)
        const short8 af = *reinterpret_cast<const short8*>(&wT[l16 * 168 + cc * 32 + g16 * 8]);
        short8 bfr[4];
#pragma unroll
        for (int ti = 0; ti < 4; ++ti)
            bfr[ti] = *reinterpret_cast<const short8*>(&Bs[(wv * 64 + ti * 16 + l16) * 40 + g16 * 8]);
#pragma unroll
        for (int ti = 0; ti < 4; ++ti)
            acc[ti] = __builtin_amdgcn_mfma_f32_16x16x32_bf16(af, bfr[ti], acc[ti], 0, 0, 0);
    }

    // ---- epilogue: D -> LDS (scaled by 1/K), then residual + fused LN ----
    __syncthreads();                     // all Bs reads done before reuse
    float* const Dld = reinterpret_cast<float*>(Bs);   // [9][264] f32 = 9504 B
#pragma unroll
    for (int ti = 0; ti < 4; ++ti) {
        const int cgl = (wv * 4 + ti) * 16 + l16;
#pragma unroll
        for (int rr = 0; rr < 4; ++rr) {
            const int o = g16 * 4 + rr;  // m89: col=lane&15, row=(lane>>4)*4+reg
            if (o < 9) Dld[o * 264 + cgl] = acc[ti][rr] * (1.f / (float)KNBR);
        }
    }
    __syncthreads();

    float2 xv[9];
    float s0 = 0.f, s1 = 0.f, s2 = 0.f, s3 = 0.f;
    if (tid < 128) {
        const int c = tid * 2;
        const float* sf = s_feats + (size_t)n * (NB * C) + c;
#pragma unroll
        for (int i = 0; i < 9; ++i) {
            const float2 d = *reinterpret_cast<const float2*>(&Dld[i * 264 + c]);
            const float2 sv = *reinterpret_cast<const float2*>(&sf[(size_t)i * C]);
            xv[i].x = d.x + sv.x;
            xv[i].y = d.y + sv.y;
        }
        s0 = xv[0].x + xv[0].y;
        s1 = xv[0].x * xv[0].x + xv[0].y * xv[0].y;
#pragma unroll
        for (int o = 1; o < 4; ++o) s2 += xv[o].x * xv[o].x + xv[o].y * xv[o].y;
#pragma unroll
        for (int o = 4; o < 9; ++o) s3 += xv[o].x * xv[o].x + xv[o].y * xv[o].y;
#pragma unroll
        for (int off = 32; off >= 1; off >>= 1) {
            s0 += __shfl_xor(s0, off);
            s1 += __shfl_xor(s1, off);
            s2 += __shfl_xor(s2, off);
            s3 += __shfl_xor(s3, off);
        }
        if (lane == 0) {
            red_s[wv][0] = s0; red_s[wv][1] = s1;
            red_s[wv][2] = s2; red_s[wv][3] = s3;
        }
    }
    __syncthreads();
    if (tid < 128) {
        s0 = red_s[0][0] + red_s[1][0];
        s1 = red_s[0][1] + red_s[1][1];
        s2 = red_s[0][2] + red_s[1][2];
        s3 = red_s[0][3] + red_s[1][3];

        const float mean0 = s0 * (1.f / 256.f);
        const float nrm0  = s1 * (1.f / 256.f) - mean0 * mean0;
        const float nrm1  = s2 * (1.f / 768.f);
        const float nrm2  = s3 * (1.f / 1280.f);
        const float r0v = rsqrtf(nrm0 + 1e-5f);
        const float r1v = rsqrtf(nrm1 + 1e-5f);
        const float r2v = rsqrtf(nrm2 + 1e-5f);

        const int c = tid * 2;
        const float2 lw0 = *reinterpret_cast<const float2*>(ln_w + c);
        const float2 lw1 = *reinterpret_cast<const float2*>(ln_w + C + c);
        const float2 lw2 = *reinterpret_cast<const float2*>(ln_w + 2 * C + c);
        const float2 lb0 = *reinterpret_cast<const float2*>(ln_b + c);

        unsigned* xo = reinterpret_cast<unsigned*>(Xb + (size_t)n * (NB * C));
        unsigned* yo = reinterpret_cast<unsigned*>(Yb + (size_t)n * (NB * C));
#pragma unroll
        for (int i = 0; i < 9; ++i) xo[i * 128 + tid] = packbf(xv[i].x, xv[i].y);
        yo[tid] = packbf((xv[0].x - mean0) * r0v * lw0.x + lb0.x,
                         (xv[0].y - mean0) * r0v * lw0.y + lb0.y);
#pragma unroll
        for (int i = 1; i < 4; ++i)
            yo[i * 128 + tid] = packbf(xv[i].x * r1v * lw1.x, xv[i].y * r1v * lw1.y);
#pragma unroll
        for (int i = 4; i < 9; ++i)
            yo[i * 128 + tid] = packbf(xv[i].x * r2v * lw2.x, xv[i].y * r2v * lw2.y);
    }
}

// ---------------------------------------------------------------------------
// Kernel 3: z(bf16) = y(bf16) @ W_ff1(f32).  M=36864 K=256 N=64.
__global__ __launch_bounds__(256) void k_ff1(const unsigned short* __restrict__ Yb,
                                             const float* __restrict__ W1,
                                             unsigned short* __restrict__ Zb) {
    __shared__ unsigned short As[128 * LDK];
    __shared__ unsigned short Bs[64 * LDK];
    const int tid = threadIdx.x;
    const int r0  = blockIdx.x * 128;
    const int wave = tid >> 6, lane = tid & 63;
    const int wm = wave >> 1, wn = wave & 1;
    const int lr = lane & 15, lg = lane >> 4;

    f32x4 acc[4][2];
#pragma unroll
    for (int a = 0; a < 4; ++a) { acc[a][0] = (f32x4){0.f,0.f,0.f,0.f}; acc[a][1] = (f32x4){0.f,0.f,0.f,0.f}; }

    for (int k0 = 0; k0 < C; k0 += 32) {
        __syncthreads();
#pragma unroll
        for (int rep = 0; rep < 4; ++rep) {
            const int e   = rep * 256 + tid;     // ush4 unit, 8 per row
            const int row = e >> 3;
            const int c4  = (e & 7) << 2;
            ush4 s = *reinterpret_cast<const ush4*>(&Yb[(size_t)(r0 + row) * C + k0 + c4]);
            *reinterpret_cast<ush4*>(&As[row * LDK + c4]) = s;
        }
#pragma unroll
        for (int rep = 0; rep < 2; ++rep) {
            const int e = rep * 256 + tid;       // float4 unit, 16 per k-row (64 n)
            const int k = e >> 4;
            const int j = (e & 15) << 2;
            const float4 v = *reinterpret_cast<const float4*>(&W1[(size_t)(k0 + k) * MID + j]);
            Bs[(j + 0) * LDK + k] = f2bf(v.x);
            Bs[(j + 1) * LDK + k] = f2bf(v.y);
            Bs[(j + 2) * LDK + k] = f2bf(v.z);
            Bs[(j + 3) * LDK + k] = f2bf(v.w);
        }
        __syncthreads();

        short8 af[4], bfr[2];
#pragma unroll
        for (int mf = 0; mf < 4; ++mf)
            af[mf] = *reinterpret_cast<const short8*>(&As[(wm * 64 + mf * 16 + lr) * LDK + lg * 8]);
#pragma unroll
        for (int nf = 0; nf < 2; ++nf)
            bfr[nf] = *reinterpret_cast<const short8*>(&Bs[(wn * 32 + nf * 16 + lr) * LDK + lg * 8]);
#pragma unroll
        for (int mf = 0; mf < 4; ++mf)
#pragma unroll
            for (int nf = 0; nf < 2; ++nf)
                acc[mf][nf] = __builtin_amdgcn_mfma_f32_16x16x32_bf16(af[mf], bfr[nf], acc[mf][nf], 0, 0, 0);
    }
#pragma unroll
    for (int mf = 0; mf < 4; ++mf)
#pragma unroll
        for (int nf = 0; nf < 2; ++nf) {
            const int col = wn * 32 + nf * 16 + lr;
#pragma unroll
            for (int r = 0; r < 4; ++r) {
                const int row = r0 + wm * 64 + mf * 16 + lg * 4 + r;
                Zb[(size_t)row * MID + col] = f2bf(acc[mf][nf][r]);
            }
        }
}

// ---------------------------------------------------------------------------
// Kernel 4: gate head. after = z0 @ W_gate; G[n][0:64]=silu, [64:192]=sigmoid.
__global__ __launch_bounds__(192) void k_gate(const unsigned short* __restrict__ Zb,
                                              const float* __restrict__ Wg,
                                              float* __restrict__ G) {
    __shared__ float wgs[64 * 192];
    __shared__ float z0s[16 * 64];
    const int tid = threadIdx.x;
    const int n0  = blockIdx.x * 16;

    for (int e = tid; e < 64 * 192; e += 192) wgs[e] = Wg[e];
    for (int e = tid; e < 16 * 64; e += 192) {
        const int r = e >> 6, m = e & 63;
        z0s[e] = bf2f(Zb[(size_t)(n0 + r) * (NB * MID) + m]);
    }
    __syncthreads();

    const int j = tid;
    for (int r = 0; r < 16; ++r) {
        float acc = 0.f;
        for (int m0 = 0; m0 < 64; m0 += 4) {
            const float4 zv = *reinterpret_cast<const float4*>(&z0s[r * 64 + m0]);
            acc = fmaf(zv.x, wgs[(m0 + 0) * 192 + j], acc);
            acc = fmaf(zv.y, wgs[(m0 + 1) * 192 + j], acc);
            acc = fmaf(zv.z, wgs[(m0 + 2) * 192 + j], acc);
            acc = fmaf(zv.w, wgs[(m0 + 3) * 192 + j], acc);
        }
        const float sig = 1.f / (1.f + expf(-acc));
        G[(size_t)(n0 + r) * 192 + j] = (j < 64) ? acc * sig : sig;
    }
}

// ---------------------------------------------------------------------------
// Kernel 5: out(f32) = gated(z) @ W_ff2 + x.  M=36864 K=64 N=256.
#define LDK64 72          // 64 + 8 pad; row stride 144B, 16B aligned
__global__ __launch_bounds__(256) void k_final(const unsigned short* __restrict__ Zb,
                                               const float* __restrict__ G,
                                               const float* __restrict__ W2,
                                               const unsigned short* __restrict__ Xb,
                                               float* __restrict__ OUT) {
    __shared__ unsigned short As[128 * LDK64];
    __shared__ unsigned short Bs[128 * LDK64];
    const int tid = threadIdx.x;
    const int r0  = blockIdx.x * 128;
    const int n0  = blockIdx.y * 128;
    const int wave = tid >> 6, lane = tid & 63;
    const int wm = wave >> 1, wn = wave & 1;
    const int lr = lane & 15, lg = lane >> 4;

    // stage A: gated-z rows (2 threads per row, 32 k each)
    {
        const int arow = tid >> 1;
        const int kh   = (tid & 1) * 32;
        const int grow = r0 + arow;
        const int nn   = grow / 9;
        const int ii   = grow - nn * 9;
        if (ii == 0) {
            const float* gp = &G[(size_t)nn * 192 + kh];
#pragma unroll
            for (int j = 0; j < 32; j += 4) {
                const float4 g = *reinterpret_cast<const float4*>(&gp[j]);
                ush4 s = { f2bf(g.x), f2bf(g.y), f2bf(g.z), f2bf(g.w) };
                *reinterpret_cast<ush4*>(&As[arow * LDK64 + kh + j]) = s;
            }
        } else {
            const float* gm = &G[(size_t)nn * 192 + ((ii < 4) ? 64 : 128) + kh];
            const unsigned short* zr = &Zb[(size_t)nn * (NB * MID) + ii * MID + kh];
#pragma unroll
            for (int j = 0; j < 32; j += 4) {
                const ush4 zv = *reinterpret_cast<const ush4*>(&zr[j]);
                const float4 g = *reinterpret_cast<const float4*>(&gm[j]);
                ush4 s = { f2bf(bf2f(zv.x) * g.x), f2bf(bf2f(zv.y) * g.y),
                           f2bf(bf2f(zv.z) * g.z), f2bf(bf2f(zv.w) * g.w) };
                *reinterpret_cast<ush4*>(&As[arow * LDK64 + kh + j]) = s;
            }
        }
    }
    // stage B: Bs[n][k] = W2[k][n0+n], full 64 x 128 tile
#pragma unroll
    for (int rep = 0; rep < 8; ++rep) {
        const int e = rep * 256 + tid;           // float4 unit, 32 per k-row
        const int k = e >> 5;
        const int j = (e & 31) << 2;
        const float4 v = *reinterpret_cast<const float4*>(&W2[(size_t)k * C + n0 + j]);
        Bs[(j + 0) * LDK64 + k] = f2bf(v.x);
        Bs[(j + 1) * LDK64 + k] = f2bf(v.y);
        Bs[(j + 2) * LDK64 + k] = f2bf(v.z);
        Bs[(j + 3) * LDK64 + k] = f2bf(v.w);
    }
    __syncthreads();

    f32x4 acc[4][4];
#pragma unroll
    for (int a = 0; a < 4; ++a)
#pragma unroll
        for (int b = 0; b < 4; ++b) acc[a][b] = (f32x4){0.f, 0.f, 0.f, 0.f};

#pragma unroll
    for (int ks = 0; ks < 2; ++ks) {
        short8 af[4], bfr[4];
#pragma unroll
        for (int mf = 0; mf < 4; ++mf)
            af[mf] = *reinterpret_cast<const short8*>(&As[(wm * 64 + mf * 16 + lr) * LDK64 + ks * 32 + lg * 8]);
#pragma unroll
        for (int nf = 0; nf < 4; ++nf)
            bfr[nf] = *reinterpret_cast<const short8*>(&Bs[(wn * 64 + nf * 16 + lr) * LDK64 + ks * 32 + lg * 8]);
#pragma unroll
        for (int mf = 0; mf < 4; ++mf)
#pragma unroll
            for (int nf = 0; nf < 4; ++nf)
                acc[mf][nf] = __builtin_amdgcn_mfma_f32_16x16x32_bf16(af[mf], bfr[nf], acc[mf][nf], 0, 0, 0);
    }

#pragma unroll
    for (int mf = 0; mf < 4; ++mf)
#pragma unroll
        for (int nf = 0; nf < 4; ++nf) {
            const int col = n0 + wn * 64 + nf * 16 + lr;
#pragma unroll
            for (int r = 0; r < 4; ++r) {
                const int row = r0 + wm * 64 + mf * 16 + lg * 4 + r;
                OUT[(size_t)row * C + col] = acc[mf][nf][r] + bf2f(Xb[(size_t)row * C + col]);
            }
        }
}

// ---------------------------------------------------------------------------
extern "C" void kernel_launch(void* const* d_in, const int* in_sizes, int n_in,
                              void* d_out, int out_size, void* d_ws, size_t ws_size,
                              hipStream_t stream) {
    const float* s_feats = (const float*)d_in[0];
    const float* s_pts   = (const float*)d_in[1];
    const float* cg      = (const float*)d_in[2];
    const float* W_proj  = (const float*)d_in[3];
    const float* ln_w    = (const float*)d_in[4];
    const float* ln_b    = (const float*)d_in[5];
    const float* W_ff1   = (const float*)d_in[6];
    const float* W_gate  = (const float*)d_in[7];
    const float* W_ff2   = (const float*)d_in[8];
    const int*   nbr     = (const int*)d_in[9];
    float* out = (float*)d_out;

    unsigned short* Hb = (unsigned short*)d_ws;            // NROWS*C bf16
    unsigned short* Xb = Hb + (size_t)NROWS * C;           // NROWS*C bf16 (shortcut)
    unsigned short* Yb = Xb + (size_t)NROWS * C;           // NROWS*C bf16 (LN output)
    unsigned short* Zb = Yb + (size_t)NROWS * C;           // NROWS*MID bf16
    float* G = (float*)(Zb + (size_t)NROWS * MID);         // N_PTS*192 f32

    k_proj  <<<dim3(NROWS / 128, 2), 256, 0, stream>>>(s_feats, W_proj, Hb);
    k_cg_ln <<<N_PTS,                256, 0, stream>>>(Hb, s_feats, s_pts, cg, nbr, ln_w, ln_b, Xb, Yb);
    k_ff1   <<<NROWS / 128,          256, 0, stream>>>(Yb, W_ff1, Zb);
    k_gate  <<<N_PTS / 16,           192, 0, stream>>>(Zb, W_gate, G);
    k_final <<<dim3(NROWS / 128, 2), 256, 0, stream>>>(Zb, G, W_ff2, Xb, out);
}

// Round 8
// 129.442 us; speedup vs baseline: 1.0331x; 1.0189x over previous
//
#include <hip/hip_runtime.h>
#include <hip/hip_bf16.h>

#define N_PTS  4096
#define NB     9
#define C      256
#define MID    64
#define KNBR   16
#define NROWS  (N_PTS * NB)          // 36864

typedef __attribute__((ext_vector_type(8))) short          short8;  // 8 bf16 (A/B frag)
typedef __attribute__((ext_vector_type(4))) float          f32x4;   // C/D frag
typedef __attribute__((ext_vector_type(4))) unsigned short ush4;
typedef __attribute__((ext_vector_type(8))) unsigned short ush8;

static __device__ __forceinline__ unsigned short f2bf(float f) {
    union { __hip_bfloat16 h; unsigned short u; } cv;
    cv.h = __float2bfloat16(f);          // RNE; pairs fuse into v_cvt_pk_bf16_f32
    return cv.u;
}
static __device__ __forceinline__ float bf2f(unsigned short s) {
    union { unsigned u; float f; } v; v.u = ((unsigned)s) << 16;
    return v.f;
}
static __device__ __forceinline__ unsigned packbf(float a, float b) {
    return (unsigned)f2bf(a) | ((unsigned)f2bf(b) << 16);
}

// ---------------------------------------------------------------------------
// Kernel 1: h(bf16) = s_feats(f32) @ W_proj(f32).  M=36864 K=256 N=256.
#define LDK 40            // 32 + 8 pad (ushorts); row stride 80B, 16B aligned
__global__ __launch_bounds__(256) void k_proj(const float* __restrict__ A,
                                              const float* __restrict__ W,
                                              unsigned short* __restrict__ H) {
    __shared__ unsigned short As[128 * LDK];
    __shared__ unsigned short Bs[128 * LDK];
    const int tid = threadIdx.x;
    const int r0  = blockIdx.x * 128;
    const int n0  = blockIdx.y * 128;
    const int wave = tid >> 6, lane = tid & 63;
    const int wm = wave >> 1, wn = wave & 1;
    const int lr = lane & 15, lg = lane >> 4;

    f32x4 acc[4][4];
#pragma unroll
    for (int a = 0; a < 4; ++a)
#pragma unroll
        for (int b = 0; b < 4; ++b) acc[a][b] = (f32x4){0.f, 0.f, 0.f, 0.f};

    for (int k0 = 0; k0 < C; k0 += 32) {
        __syncthreads();
#pragma unroll
        for (int rep = 0; rep < 4; ++rep) {
            const int e   = rep * 256 + tid;      // float4 unit, 8 per row
            const int row = e >> 3;
            const int c4  = (e & 7) << 2;
            const float4 v = *reinterpret_cast<const float4*>(&A[(size_t)(r0 + row) * C + k0 + c4]);
            ush4 s = { f2bf(v.x), f2bf(v.y), f2bf(v.z), f2bf(v.w) };
            *reinterpret_cast<ush4*>(&As[row * LDK + c4]) = s;
        }
#pragma unroll
        for (int rep = 0; rep < 4; ++rep) {
            const int e = rep * 256 + tid;        // float4 unit, 32 per k-row
            const int k = e >> 5;
            const int j = (e & 31) << 2;
            const float4 v = *reinterpret_cast<const float4*>(&W[(size_t)(k0 + k) * C + n0 + j]);
            Bs[(j + 0) * LDK + k] = f2bf(v.x);
            Bs[(j + 1) * LDK + k] = f2bf(v.y);
            Bs[(j + 2) * LDK + k] = f2bf(v.z);
            Bs[(j + 3) * LDK + k] = f2bf(v.w);
        }
        __syncthreads();

        short8 af[4], bfr[4];
#pragma unroll
        for (int mf = 0; mf < 4; ++mf)
            af[mf] = *reinterpret_cast<const short8*>(&As[(wm * 64 + mf * 16 + lr) * LDK + lg * 8]);
#pragma unroll
        for (int nf = 0; nf < 4; ++nf)
            bfr[nf] = *reinterpret_cast<const short8*>(&Bs[(wn * 64 + nf * 16 + lr) * LDK + lg * 8]);
#pragma unroll
        for (int mf = 0; mf < 4; ++mf)
#pragma unroll
            for (int nf = 0; nf < 4; ++nf)
                acc[mf][nf] = __builtin_amdgcn_mfma_f32_16x16x32_bf16(af[mf], bfr[nf], acc[mf][nf], 0, 0, 0);
    }
#pragma unroll
    for (int mf = 0; mf < 4; ++mf)
#pragma unroll
        for (int nf = 0; nf < 4; ++nf) {
            const int col = n0 + wn * 64 + nf * 16 + lr;
#pragma unroll
            for (int r = 0; r < 4; ++r) {
                const int row = r0 + wm * 64 + mf * 16 + lg * 4 + r;
                H[(size_t)row * C + col] = f2bf(acc[mf][nf][r]);
            }
        }
}

// ---------------------------------------------------------------------------
// Kernel 2: CG contraction via MFMA + residual + fused per-degree LN.
// Same proven math/layout as round 7; schedule changed:
//  - register prefetch one chunk ahead (T14): gather loads for chunk cc+1
//    issue right after chunk cc's ds_writes -> latency hides under
//    barrier + fragment reads + MFMA.
//  - cg staging aliases Bs (cg dead after wT build) -> LDS 26.5 KB,
//    6 blocks/CU.
__global__ __launch_bounds__(256) void k_cg_ln(const unsigned short* __restrict__ Hb,
                                               const float* __restrict__ s_feats,
                                               const float* __restrict__ pts,
                                               const float* __restrict__ cg,
                                               const int*   __restrict__ nbr,
                                               const float* __restrict__ ln_w,
                                               const float* __restrict__ ln_b,
                                               unsigned short* __restrict__ Xb,
                                               unsigned short* __restrict__ Yb) {
    __shared__ unsigned short Bs[256 * 40];      // 20 KB; start aliased as cg staging
    __shared__ unsigned short wT[16 * 168];      // 5.25 KB, A operand (zero-padded)
    __shared__ float sh_s[KNBR][NB];
    __shared__ int   idx_s[KNBR];
    __shared__ float red_s[2][4];

    float* const cg_s = reinterpret_cast<float*>(Bs);   // alias: dead before 1st Bs write

    const int tid  = threadIdx.x;
    const int n    = blockIdx.x;
    const int wv   = tid >> 6;
    const int lane = tid & 63;
    const int g16  = lane >> 4;
    const int l16  = lane & 15;

    // ---- prologue: cg -> cg_s(=Bs), zero wT, SH + neighbor indices ----
    {
        unsigned* w32 = reinterpret_cast<unsigned*>(wT);
        for (int e = tid; e < (16 * 168) / 2; e += 256) w32[e] = 0u;
    }
    for (int e = tid; e < 729; e += 256) cg_s[e] = cg[e];
    if (tid < KNBR) {
        const int idx = nbr[n * KNBR + tid];
        idx_s[tid] = idx;
        const float px = pts[idx * 3 + 0] - pts[n * 3 + 0];
        const float py = pts[idx * 3 + 1] - pts[n * 3 + 1];
        const float pz = pts[idx * 3 + 2] - pts[n * 3 + 2];
        const float r  = sqrtf(px * px + py * py + pz * pz);
        const float iv = 1.f / (r + 1e-8f);
        const float dx = px * iv, dy = py * iv, dz = pz * iv;
        const float c1 = 0.4886025119029199f;
        const float c2 = 1.0925484305920792f;
        sh_s[tid][0] = 0.28209479177387814f;
        sh_s[tid][1] = c1 * dy;
        sh_s[tid][2] = c1 * dz;
        sh_s[tid][3] = c1 * dx;
        sh_s[tid][4] = c2 * dx * dy;
        sh_s[tid][5] = c2 * dy * dz;
        sh_s[tid][6] = 0.31539156525252005f * (3.f * dz * dz - 1.f);
        sh_s[tid][7] = c2 * dx * dz;
        sh_s[tid][8] = 0.5462742152960396f * (dx * dx - dy * dy);
    }
    __syncthreads();     // idx_s, sh_s, cg_s visible

    // ---- staging geometry: thread stages ki-row r, c-segment s (32 c) ----
    const int r = tid & 31;     // ki row within chunk
    const int s = tid >> 5;     // 32-channel segment

    // issue chunk-0 gather loads NOW; latency hides under the wT build below
    ush8 q0, q1, q2, q3;
    {
        const int ki = r;                     // chunk 0, all rows valid
        const int kk = ki / 9;
        const int ii = ki - kk * 9;
        const unsigned short* hrow = Hb + (size_t)(idx_s[kk] * NB + ii) * C + s * 32;
        q0 = *reinterpret_cast<const ush8*>(hrow + 0);
        q1 = *reinterpret_cast<const ush8*>(hrow + 8);
        q2 = *reinterpret_cast<const ush8*>(hrow + 16);
        q3 = *reinterpret_cast<const ush8*>(hrow + 24);
    }

    // ---- build wT[o][ki] while chunk-0 loads are in flight ----
    for (int t = tid; t < 144 * 9; t += 256) {
        const int ki = t / 9;
        const int o  = t - ki * 9;
        const int kk = ki / 9;
        const int ii = ki - kk * 9;
        float sv = 0.f;
#pragma unroll
        for (int j = 0; j < 9; ++j) sv = fmaf(sh_s[kk][j], cg_s[ii * 81 + j * 9 + o], sv);
        wT[o * 168 + ki] = f2bf(sv);
    }

    f32x4 acc[4];
#pragma unroll
    for (int i = 0; i < 4; ++i) acc[i] = (f32x4){0.f, 0.f, 0.f, 0.f};

    for (int cc = 0; cc < 5; ++cc) {
        const int nrows = (cc == 4) ? 16 : 32;   // ki 144..159 have w=0: skip staging

        __syncthreads();   // cc==0: wT build + cg_s reads done; cc>0: prev reads drained

        // write current chunk (vmcnt waits for this chunk's loads)
        if (r < nrows) {
            const unsigned short* qe;
            qe = reinterpret_cast<const unsigned short*>(&q0);
#pragma unroll
            for (int e = 0; e < 8; ++e) Bs[(s * 32 + 0 * 8 + e) * 40 + r] = qe[e];
            qe = reinterpret_cast<const unsigned short*>(&q1);
#pragma unroll
            for (int e = 0; e < 8; ++e) Bs[(s * 32 + 1 * 8 + e) * 40 + r] = qe[e];
            qe = reinterpret_cast<const unsigned short*>(&q2);
#pragma unroll
            for (int e = 0; e < 8; ++e) Bs[(s * 32 + 2 * 8 + e) * 40 + r] = qe[e];
            qe = reinterpret_cast<const unsigned short*>(&q3);
#pragma unroll
            for (int e = 0; e < 8; ++e) Bs[(s * 32 + 3 * 8 + e) * 40 + r] = qe[e];
        }

        // prefetch NEXT chunk into registers (one ahead, T14)
        if (cc < 4) {
            const int kin   = (cc + 1) * 32 + r;
            const bool vldn = (kin < 144);
            if (vldn) {
                const int kk = kin / 9;
                const int ii = kin - kk * 9;
                const unsigned short* hrow = Hb + (size_t)(idx_s[kk] * NB + ii) * C + s * 32;
                q0 = *reinterpret_cast<const ush8*>(hrow + 0);
                q1 = *reinterpret_cast<const ush8*>(hrow + 8);
                q2 = *reinterpret_cast<const ush8*>(hrow + 16);
                q3 = *reinterpret_cast<const ush8*>(hrow + 24);
            }
        }

        __syncthreads();   // staged chunk visible

        // fragments exactly like k_proj (proven layout)
        const short8 af = *reinterpret_cast<const short8*>(&wT[l16 * 168 + cc * 32 + g16 * 8]);
        short8 bfr[4];
#pragma unroll
        for (int ti = 0; ti < 4; ++ti)
            bfr[ti] = *reinterpret_cast<const short8*>(&Bs[(wv * 64 + ti * 16 + l16) * 40 + g16 * 8]);
#pragma unroll
        for (int ti = 0; ti < 4; ++ti)
            acc[ti] = __builtin_amdgcn_mfma_f32_16x16x32_bf16(af, bfr[ti], acc[ti], 0, 0, 0);
    }

    // ---- epilogue: D -> LDS (scaled by 1/K), then residual + fused LN ----
    __syncthreads();                     // all Bs reads done before reuse
    float* const Dld = reinterpret_cast<float*>(Bs);   // [9][264] f32 = 9504 B
#pragma unroll
    for (int ti = 0; ti < 4; ++ti) {
        const int cgl = (wv * 4 + ti) * 16 + l16;
#pragma unroll
        for (int rr = 0; rr < 4; ++rr) {
            const int o = g16 * 4 + rr;  // m89: col=lane&15, row=(lane>>4)*4+reg
            if (o < 9) Dld[o * 264 + cgl] = acc[ti][rr] * (1.f / (float)KNBR);
        }
    }
    __syncthreads();

    float2 xv[9];
    float s0 = 0.f, s1 = 0.f, s2 = 0.f, s3 = 0.f;
    if (tid < 128) {
        const int c = tid * 2;
        const float* sf = s_feats + (size_t)n * (NB * C) + c;
#pragma unroll
        for (int i = 0; i < 9; ++i) {
            const float2 d  = *reinterpret_cast<const float2*>(&Dld[i * 264 + c]);
            const float2 sv = *reinterpret_cast<const float2*>(&sf[(size_t)i * C]);
            xv[i].x = d.x + sv.x;
            xv[i].y = d.y + sv.y;
        }
        s0 = xv[0].x + xv[0].y;
        s1 = xv[0].x * xv[0].x + xv[0].y * xv[0].y;
#pragma unroll
        for (int o = 1; o < 4; ++o) s2 += xv[o].x * xv[o].x + xv[o].y * xv[o].y;
#pragma unroll
        for (int o = 4; o < 9; ++o) s3 += xv[o].x * xv[o].x + xv[o].y * xv[o].y;
#pragma unroll
        for (int off = 32; off >= 1; off >>= 1) {
            s0 += __shfl_xor(s0, off);
            s1 += __shfl_xor(s1, off);
            s2 += __shfl_xor(s2, off);
            s3 += __shfl_xor(s3, off);
        }
        if (lane == 0) {
            red_s[wv][0] = s0; red_s[wv][1] = s1;
            red_s[wv][2] = s2; red_s[wv][3] = s3;
        }
    }
    __syncthreads();
    if (tid < 128) {
        s0 = red_s[0][0] + red_s[1][0];
        s1 = red_s[0][1] + red_s[1][1];
        s2 = red_s[0][2] + red_s[1][2];
        s3 = red_s[0][3] + red_s[1][3];

        const float mean0 = s0 * (1.f / 256.f);
        const float nrm0  = s1 * (1.f / 256.f) - mean0 * mean0;
        const float nrm1  = s2 * (1.f / 768.f);
        const float nrm2  = s3 * (1.f / 1280.f);
        const float r0v = rsqrtf(nrm0 + 1e-5f);
        const float r1v = rsqrtf(nrm1 + 1e-5f);
        const float r2v = rsqrtf(nrm2 + 1e-5f);

        const int c = tid * 2;
        const float2 lw0 = *reinterpret_cast<const float2*>(ln_w + c);
        const float2 lw1 = *reinterpret_cast<const float2*>(ln_w + C + c);
        const float2 lw2 = *reinterpret_cast<const float2*>(ln_w + 2 * C + c);
        const float2 lb0 = *reinterpret_cast<const float2*>(ln_b + c);

        unsigned* xo = reinterpret_cast<unsigned*>(Xb + (size_t)n * (NB * C));
        unsigned* yo = reinterpret_cast<unsigned*>(Yb + (size_t)n * (NB * C));
#pragma unroll
        for (int i = 0; i < 9; ++i) xo[i * 128 + tid] = packbf(xv[i].x, xv[i].y);
        yo[tid] = packbf((xv[0].x - mean0) * r0v * lw0.x + lb0.x,
                         (xv[0].y - mean0) * r0v * lw0.y + lb0.y);
#pragma unroll
        for (int i = 1; i < 4; ++i)
            yo[i * 128 + tid] = packbf(xv[i].x * r1v * lw1.x, xv[i].y * r1v * lw1.y);
#pragma unroll
        for (int i = 4; i < 9; ++i)
            yo[i * 128 + tid] = packbf(xv[i].x * r2v * lw2.x, xv[i].y * r2v * lw2.y);
    }
}

// ---------------------------------------------------------------------------
// Kernel 3: z(bf16) = y(bf16) @ W_ff1(f32).  M=36864 K=256 N=64.
__global__ __launch_bounds__(256) void k_ff1(const unsigned short* __restrict__ Yb,
                                             const float* __restrict__ W1,
                                             unsigned short* __restrict__ Zb) {
    __shared__ unsigned short As[128 * LDK];
    __shared__ unsigned short Bs[64 * LDK];
    const int tid = threadIdx.x;
    const int r0  = blockIdx.x * 128;
    const int wave = tid >> 6, lane = tid & 63;
    const int wm = wave >> 1, wn = wave & 1;
    const int lr = lane & 15, lg = lane >> 4;

    f32x4 acc[4][2];
#pragma unroll
    for (int a = 0; a < 4; ++a) { acc[a][0] = (f32x4){0.f,0.f,0.f,0.f}; acc[a][1] = (f32x4){0.f,0.f,0.f,0.f}; }

    for (int k0 = 0; k0 < C; k0 += 32) {
        __syncthreads();
#pragma unroll
        for (int rep = 0; rep < 4; ++rep) {
            const int e   = rep * 256 + tid;     // ush4 unit, 8 per row
            const int row = e >> 3;
            const int c4  = (e & 7) << 2;
            ush4 s = *reinterpret_cast<const ush4*>(&Yb[(size_t)(r0 + row) * C + k0 + c4]);
            *reinterpret_cast<ush4*>(&As[row * LDK + c4]) = s;
        }
#pragma unroll
        for (int rep = 0; rep < 2; ++rep) {
            const int e = rep * 256 + tid;       // float4 unit, 16 per k-row (64 n)
            const int k = e >> 4;
            const int j = (e & 15) << 2;
            const float4 v = *reinterpret_cast<const float4*>(&W1[(size_t)(k0 + k) * MID + j]);
            Bs[(j + 0) * LDK + k] = f2bf(v.x);
            Bs[(j + 1) * LDK + k] = f2bf(v.y);
            Bs[(j + 2) * LDK + k] = f2bf(v.z);
            Bs[(j + 3) * LDK + k] = f2bf(v.w);
        }
        __syncthreads();

        short8 af[4], bfr[2];
#pragma unroll
        for (int mf = 0; mf < 4; ++mf)
            af[mf] = *reinterpret_cast<const short8*>(&As[(wm * 64 + mf * 16 + lr) * LDK + lg * 8]);
#pragma unroll
        for (int nf = 0; nf < 2; ++nf)
            bfr[nf] = *reinterpret_cast<const short8*>(&Bs[(wn * 32 + nf * 16 + lr) * LDK + lg * 8]);
#pragma unroll
        for (int mf = 0; mf < 4; ++mf)
#pragma unroll
            for (int nf = 0; nf < 2; ++nf)
                acc[mf][nf] = __builtin_amdgcn_mfma_f32_16x16x32_bf16(af[mf], bfr[nf], acc[mf][nf], 0, 0, 0);
    }
#pragma unroll
    for (int mf = 0; mf < 4; ++mf)
#pragma unroll
        for (int nf = 0; nf < 2; ++nf) {
            const int col = wn * 32 + nf * 16 + lr;
#pragma unroll
            for (int r = 0; r < 4; ++r) {
                const int row = r0 + wm * 64 + mf * 16 + lg * 4 + r;
                Zb[(size_t)row * MID + col] = f2bf(acc[mf][nf][r]);
            }
        }
}

// ---------------------------------------------------------------------------
// Kernel 4: gate head. after = z0 @ W_gate; G[n][0:64]=silu, [64:192]=sigmoid.
__global__ __launch_bounds__(192) void k_gate(const unsigned short* __restrict__ Zb,
                                              const float* __restrict__ Wg,
                                              float* __restrict__ G) {
    __shared__ float wgs[64 * 192];
    __shared__ float z0s[16 * 64];
    const int tid = threadIdx.x;
    const int n0  = blockIdx.x * 16;

    for (int e = tid; e < 64 * 192; e += 192) wgs[e] = Wg[e];
    for (int e = tid; e < 16 * 64; e += 192) {
        const int r = e >> 6, m = e & 63;
        z0s[e] = bf2f(Zb[(size_t)(n0 + r) * (NB * MID) + m]);
    }
    __syncthreads();

    const int j = tid;
    for (int r = 0; r < 16; ++r) {
        float acc = 0.f;
        for (int m0 = 0; m0 < 64; m0 += 4) {
            const float4 zv = *reinterpret_cast<const float4*>(&z0s[r * 64 + m0]);
            acc = fmaf(zv.x, wgs[(m0 + 0) * 192 + j], acc);
            acc = fmaf(zv.y, wgs[(m0 + 1) * 192 + j], acc);
            acc = fmaf(zv.z, wgs[(m0 + 2) * 192 + j], acc);
            acc = fmaf(zv.w, wgs[(m0 + 3) * 192 + j], acc);
        }
        const float sig = 1.f / (1.f + expf(-acc));
        G[(size_t)(n0 + r) * 192 + j] = (j < 64) ? acc * sig : sig;
    }
}

// ---------------------------------------------------------------------------
// Kernel 5: out(f32) = gated(z) @ W_ff2 + x.  M=36864 K=64 N=256.
#define LDK64 72          // 64 + 8 pad; row stride 144B, 16B aligned
__global__ __launch_bounds__(256) void k_final(const unsigned short* __restrict__ Zb,
                                               const float* __restrict__ G,
                                               const float* __restrict__ W2,
                                               const unsigned short* __restrict__ Xb,
                                               float* __restrict__ OUT) {
    __shared__ unsigned short As[128 * LDK64];
    __shared__ unsigned short Bs[128 * LDK64];
    const int tid = threadIdx.x;
    const int r0  = blockIdx.x * 128;
    const int n0  = blockIdx.y * 128;
    const int wave = tid >> 6, lane = tid & 63;
    const int wm = wave >> 1, wn = wave & 1;
    const int lr = lane & 15, lg = lane >> 4;

    // stage A: gated-z rows (2 threads per row, 32 k each)
    {
        const int arow = tid >> 1;
        const int kh   = (tid & 1) * 32;
        const int grow = r0 + arow;
        const int nn   = grow / 9;
        const int ii   = grow - nn * 9;
        if (ii == 0) {
            const float* gp = &G[(size_t)nn * 192 + kh];
#pragma unroll
            for (int j = 0; j < 32; j += 4) {
                const float4 g = *reinterpret_cast<const float4*>(&gp[j]);
                ush4 s = { f2bf(g.x), f2bf(g.y), f2bf(g.z), f2bf(g.w) };
                *reinterpret_cast<ush4*>(&As[arow * LDK64 + kh + j]) = s;
            }
        } else {
            const float* gm = &G[(size_t)nn * 192 + ((ii < 4) ? 64 : 128) + kh];
            const unsigned short* zr = &Zb[(size_t)nn * (NB * MID) + ii * MID + kh];
#pragma unroll
            for (int j = 0; j < 32; j += 4) {
                const ush4 zv = *reinterpret_cast<const ush4*>(&zr[j]);
                const float4 g = *reinterpret_cast<const float4*>(&gm[j]);
                ush4 s = { f2bf(bf2f(zv.x) * g.x), f2bf(bf2f(zv.y) * g.y),
                           f2bf(bf2f(zv.z) * g.z), f2bf(bf2f(zv.w) * g.w) };
                *reinterpret_cast<ush4*>(&As[arow * LDK64 + kh + j]) = s;
            }
        }
    }
    // stage B: Bs[n][k] = W2[k][n0+n], full 64 x 128 tile
#pragma unroll
    for (int rep = 0; rep < 8; ++rep) {
        const int e = rep * 256 + tid;           // float4 unit, 32 per k-row
        const int k = e >> 5;
        const int j = (e & 31) << 2;
        const float4 v = *reinterpret_cast<const float4*>(&W2[(size_t)k * C + n0 + j]);
        Bs[(j + 0) * LDK64 + k] = f2bf(v.x);
        Bs[(j + 1) * LDK64 + k] = f2bf(v.y);
        Bs[(j + 2) * LDK64 + k] = f2bf(v.z);
        Bs[(j + 3) * LDK64 + k] = f2bf(v.w);
    }
    __syncthreads();

    f32x4 acc[4][4];
#pragma unroll
    for (int a = 0; a < 4; ++a)
#pragma unroll
        for (int b = 0; b < 4; ++b) acc[a][b] = (f32x4){0.f, 0.f, 0.f, 0.f};

#pragma unroll
    for (int ks = 0; ks < 2; ++ks) {
        short8 af[4], bfr[4];
#pragma unroll
        for (int mf = 0; mf < 4; ++mf)
            af[mf] = *reinterpret_cast<const short8*>(&As[(wm * 64 + mf * 16 + lr) * LDK64 + ks * 32 + lg * 8]);
#pragma unroll
        for (int nf = 0; nf < 4; ++nf)
            bfr[nf] = *reinterpret_cast<const short8*>(&Bs[(wn * 64 + nf * 16 + lr) * LDK64 + ks * 32 + lg * 8]);
#pragma unroll
        for (int mf = 0; mf < 4; ++mf)
#pragma unroll
            for (int nf = 0; nf < 4; ++nf)
                acc[mf][nf] = __builtin_amdgcn_mfma_f32_16x16x32_bf16(af[mf], bfr[nf], acc[mf][nf], 0, 0, 0);
    }

#pragma unroll
    for (int mf = 0; mf < 4; ++mf)
#pragma unroll
        for (int nf = 0; nf < 4; ++nf) {
            const int col = n0 + wn * 64 + nf * 16 + lr;
#pragma unroll
            for (int r = 0; r < 4; ++r) {
                const int row = r0 + wm * 64 + mf * 16 + lg * 4 + r;
                OUT[(size_t)row * C + col] = acc[mf][nf][r] + bf2f(Xb[(size_t)row * C + col]);
            }
        }
}

// ---------------------------------------------------------------------------
extern "C" void kernel_launch(void* const* d_in, const int* in_sizes, int n_in,
                              void* d_out, int out_size, void* d_ws, size_t ws_size,
                              hipStream_t stream) {
    const float* s_feats = (const float*)d_in[0];
    const float* s_pts   = (const float*)d_in[1];
    const float* cg      = (const float*)d_in[2];
    const float* W_proj  = (const float*)d_in[3];
    const float* ln_w    = (const float*)d_in[4];
    const float* ln_b    = (const float*)d_in[5];
    const float* W_ff1   = (const float*)d_in[6];
    const float* W_gate  = (const float*)d_in[7];
    const float* W_ff2   = (const float*)d_in[8];
    const int*   nbr     = (const int*)d_in[9];
    float* out = (float*)d_out;

    unsigned short* Hb = (unsigned short*)d_ws;            // NROWS*C bf16
    unsigned short* Xb = Hb + (size_t)NROWS * C;           // NROWS*C bf16 (shortcut)
    unsigned short* Yb = Xb + (size_t)NROWS * C;           // NROWS*C bf16 (LN output)
    unsigned short* Zb = Yb + (size_t)NROWS * C;           // NROWS*MID bf16
    float* G = (float*)(Zb + (size_t)NROWS * MID);         // N_PTS*192 f32

    k_proj  <<<dim3(NROWS / 128, 2), 256, 0, stream>>>(s_feats, W_proj, Hb);
    k_cg_ln <<<N_PTS,                256, 0, stream>>>(Hb, s_feats, s_pts, cg, nbr, ln_w, ln_b, Xb, Yb);
    k_ff1   <<<NROWS / 128,          256, 0, stream>>>(Yb, W_ff1, Zb);
    k_gate  <<<N_PTS / 16,           192, 0, stream>>>(Zb, W_gate, G);
    k_final <<<dim3(NROWS / 128, 2), 256, 0, stream>>>(Zb, G, W_ff2, Xb, out);
}